// Round 1
// baseline (363.556 us; speedup 1.0000x reference)
//
#include <hip/hip_runtime.h>
#include <hip/hip_bf16.h>

// NeighbourhoodAttnBlock: B=2, H=W=64, D=512, NH=8, DH=64, KERNEL=7
// *** INSTRUMENTATION ROUND ***
// Logic identical to the 135.5us best kernel, but each kernel body is
// repeated R times (idempotent recompute, laundered addresses, inter-rep
// barriers) so every dispatch exceeds the ~45us fill kernels and surfaces
// in the rocprof top-5 WITH counters. True per-stage time = dispatch/R.
// R values: cvt x16, qkv-gemm x4, attn x6, out-gemm x6. Revert next round.

typedef __bf16 bf16x8 __attribute__((ext_vector_type(8)));
typedef __bf16 bf16x4 __attribute__((ext_vector_type(4)));
typedef float  f32x4  __attribute__((ext_vector_type(4)));

__global__ __launch_bounds__(256) void cvt_all(
    const float* __restrict__ x, const float* __restrict__ wq,
    const float* __restrict__ wo, __bf16* __restrict__ xb,
    __bf16* __restrict__ wqb, __bf16* __restrict__ wob) {
  // 655360 chunks of 2x f32x4 (32B read / 16B write per thread)
  int i = blockIdx.x * 256 + threadIdx.x;
  const float* src;
  __bf16* dst;
  int j = i;
  if (j < 524288) {
    src = x; dst = xb;
  } else if (j < 524288 + 98304) {
    j -= 524288; src = wq; dst = wqb;
  } else {
    j -= 524288 + 98304; src = wo; dst = wob;
  }
#pragma unroll 1
  for (int rep = 0; rep < 16; ++rep) {
    int jj = j;
    asm volatile("" : "+v"(jj));  // opaque per-rep index: no CSE/DSE
    f32x4 v0 = ((const f32x4*)src)[(size_t)jj * 2];
    f32x4 v1 = ((const f32x4*)src)[(size_t)jj * 2 + 1];
    bf16x8 o;
    o[0] = (__bf16)v0[0]; o[1] = (__bf16)v0[1];
    o[2] = (__bf16)v0[2]; o[3] = (__bf16)v0[3];
    o[4] = (__bf16)v1[0]; o[5] = (__bf16)v1[1];
    o[6] = (__bf16)v1[2]; o[7] = (__bf16)v1[3];
    ((bf16x8*)dst)[jj] = o;
  }
}

__device__ __forceinline__ void gload_lds16(const __bf16* g, __bf16* l) {
  __builtin_amdgcn_global_load_lds(
      (const __attribute__((address_space(1))) void*)g,
      (__attribute__((address_space(3))) void*)l, 16, 0, 0);
}

// C[i][e] = sum_d A[i][d] * W[e][d];  A:[M,512], W:[E,512] row-major bf16.
// 128xBN block tile, 4 waves x (64 x BN/2). BK=64 via two contiguous 32-col
// half-buffers (global_load_lds needs unpadded contiguity).
template <bool QKV, int BN, int RREP>
__global__ __launch_bounds__(256, 3) void gemm_lds(
    const __bf16* __restrict__ A, const __bf16* __restrict__ W,
    __bf16* __restrict__ qo, __bf16* __restrict__ ko, __bf16* __restrict__ vo,
    float* __restrict__ co, int etiles) {
  constexpr int K = 512;
  constexpr int NT = BN / 32;
  constexpr int WHALF = BN * 32;
  __shared__ alignas(16) __bf16 Al[2 * 128 * 32];
  __shared__ alignas(16) __bf16 Wl[2 * WHALF];
  const int tid = threadIdx.x;
  const int wv = tid >> 6, lane = tid & 63;
  const int n16 = lane & 15, quad = lane >> 4;
  const int bi = blockIdx.x / etiles, be = blockIdx.x % etiles;
  const int i0 = bi << 7, e0 = be * BN;
  const int wm = (wv & 1) << 6, we = (wv >> 1) * (BN / 2);

  const int srow = (wv << 4) + (lane >> 2);
  const int scol = (lane & 3) << 3;
  const __bf16* gA = A + (size_t)(i0 + srow) * K + scol;
  const __bf16* gW = W + (size_t)(e0 + srow) * K + scol;
  const int soff = (wv << 9) + (lane << 3);

#pragma unroll 1
  for (int rep = 0; rep < RREP; ++rep) {
    int rk = 0;
    asm volatile("" : "+v"(rk));  // runtime 0, opaque: defeats cross-rep opt

    f32x4 acc[4][NT];
#pragma unroll
    for (int a = 0; a < 4; ++a)
#pragma unroll
      for (int b = 0; b < NT; ++b) acc[a][b] = (f32x4){0.f, 0.f, 0.f, 0.f};

    for (int k0 = 0; k0 < K; k0 += 64) {
      if (k0 | rep) __syncthreads();
#pragma unroll
      for (int h = 0; h < 2; ++h) {
        gload_lds16(gA + k0 + rk + h * 32, &Al[h * 4096 + soff]);
        gload_lds16(gA + (size_t)64 * K + k0 + rk + h * 32,
                    &Al[h * 4096 + 64 * 32 + soff]);
        gload_lds16(gW + k0 + rk + h * 32, &Wl[h * WHALF + soff]);
        if (BN == 128)
          gload_lds16(gW + (size_t)64 * K + k0 + rk + h * 32,
                      &Wl[h * WHALF + 64 * 32 + soff]);
      }
      __syncthreads();

#pragma unroll
      for (int h = 0; h < 2; ++h) {
        bf16x8 af[4], wf[NT];
#pragma unroll
        for (int t = 0; t < 4; ++t)
          af[t] = *(const bf16x8*)&Al[h * 4096 + (wm + t * 16 + n16) * 32 +
                                      quad * 8];
#pragma unroll
        for (int t = 0; t < NT; ++t)
          wf[t] = *(const bf16x8*)&Wl[h * WHALF + (we + t * 16 + n16) * 32 +
                                      quad * 8];
#pragma unroll
        for (int mt = 0; mt < 4; ++mt)
#pragma unroll
          for (int nt = 0; nt < NT; ++nt)
            acc[mt][nt] = __builtin_amdgcn_mfma_f32_16x16x32_bf16(
                af[mt], wf[nt], acc[mt][nt], 0, 0, 0);
      }
    }

#pragma unroll
    for (int mt = 0; mt < 4; ++mt)
#pragma unroll
      for (int nt = 0; nt < NT; ++nt) {
        f32x4 f = acc[mt][nt];
        int e = e0 + we + nt * 16 + n16 + rk;  // rk laundered (=0)
#pragma unroll
        for (int rg = 0; rg < 4; ++rg) {
          int i = i0 + wm + mt * 16 + quad * 4 + rg;
          float val = f[rg];
          if (QKV) {
            int t = e >> 9, head = (e >> 6) & 7, dh = e & 63;
            int b = i >> 12, s = i & 4095;
            int bh = b * 8 + head;
            if (t == 2) {
              vo[((size_t)bh * 64 + dh) * 4096 + s] = (__bf16)val;  // vt
            } else {
              size_t off = (((size_t)bh * 4096) + s) * 64 + dh;
              ((t == 0) ? qo : ko)[off] = (__bf16)val;
            }
          } else {
            co[(size_t)i * 512 + e] = val;  // fp32 output
          }
        }
      }
  }
}

// MFMA neighbourhood attention (R7/R12 one-shot config, best known).
// One workgroup per (bh, 8x8 query tile). Phase 1: coop-load full K-window
// (14x16 keys x 64 dh, xor-swizzled) into r1; QK^T via ds_read_b128;
// softmax in regs; P -> per-wave sbuf. Phase 2: barrier; coop-load V-window
// into r1 as vwin[dh][232]; PV fully from LDS.
__global__ __launch_bounds__(256) void attn_mfma(
    const __bf16* __restrict__ q, const __bf16* __restrict__ k,
    const __bf16* __restrict__ vt, __bf16* __restrict__ out) {
  __shared__ alignas(16) __bf16 r1[14848];         // kwin / vwin[64][232]
  __shared__ alignas(16) __bf16 sbuf[4][16][232];  // per-wave P (padded)
  const int tid = threadIdx.x;
  const int wv = tid >> 6;
  const int lane = tid & 63;
  const int n16 = lane & 15, quad = lane >> 4;
  const int bh0 = blockIdx.x >> 6;
  const int tile = blockIdx.x & 63;
  const int qh0 = (tile >> 3) << 3, qw0 = (tile & 7) << 3;
  int wh0 = qh0 - 3; wh0 = wh0 < 0 ? 0 : (wh0 > 50 ? 50 : wh0);
  int wc0 = qw0 - 3; wc0 = wc0 < 0 ? 0 : (wc0 > 48 ? 48 : wc0);
  wc0 &= ~1;  // -> multiple of 4; window covers [qw0-3, qw0+10]

#pragma unroll 1
  for (int rep = 0; rep < 6; ++rep) {
    if (rep) __syncthreads();  // r1 still read by PV of previous rep
    int bh = bh0;
    asm volatile("" : "+v"(bh));  // opaque per-rep base
    const size_t base = (size_t)bh * 4096 * 64;

    // ---- Q A-frags (issue first; fly during coop K load) ----
    const int qi_a = wv * 16 + n16;
    const int sqa = (qh0 + (qi_a >> 3)) * 64 + qw0 + (qi_a & 7);
    const __bf16* qp = q + base + (size_t)sqa * 64 + quad * 8;
    bf16x8 aq0 = *(const bf16x8*)qp;
    bf16x8 aq1 = *(const bf16x8*)(qp + 32);

    // ---- coop load K window: 14 rows x 2 KB contiguous each ----
    const __bf16* kbase = k + base;
#pragma unroll
    for (int i = 0; i < 7; ++i) {
      int ch = i * 256 + tid;           // 1792 16-B chunks
      int kr = ch >> 7, wi = ch & 127;
      int kc = wi >> 3, dh8 = wi & 7;
      bf16x8 d = *(const bf16x8*)(kbase +
          (size_t)((wh0 + kr) * 64 + wc0 + kc) * 64 + dh8 * 8);
      *(bf16x8*)&r1[(kr * 16 + kc) * 64 + ((dh8 ^ (kc & 7)) * 8)] = d;
    }
    __syncthreads();

    // ---- scores from LDS ----
    f32x4 S[14];
    const int skw = wc0 + n16;
    const int sw1 = ((quad ^ (n16 & 7)) * 8);
    const int sw2 = (((4 + quad) ^ (n16 & 7)) * 8);
#pragma unroll
    for (int nt = 0; nt < 14; ++nt) {
      int key = nt * 16 + n16;
      bf16x8 b0 = *(const bf16x8*)&r1[key * 64 + sw1];
      bf16x8 b1 = *(const bf16x8*)&r1[key * 64 + sw2];
      f32x4 s = {0.f, 0.f, 0.f, 0.f};
      s = __builtin_amdgcn_mfma_f32_16x16x32_bf16(aq0, b0, s, 0, 0, 0);
      s = __builtin_amdgcn_mfma_f32_16x16x32_bf16(aq1, b1, s, 0, 0, 0);
      S[nt] = s;
    }

    // ---- exact mask + scale + row max ----
    float mx[4] = {-1e30f, -1e30f, -1e30f, -1e30f};
#pragma unroll
    for (int reg = 0; reg < 4; ++reg) {
      int qi = wv * 16 + quad * 4 + reg;
      int qh = qh0 + (qi >> 3), qw = qw0 + (qi & 7);
      int sh = qh - 3; sh = sh < 0 ? 0 : (sh > 57 ? 57 : sh);
      int sw = qw - 3; sw = sw < 0 ? 0 : (sw > 57 ? 57 : sw);
      bool wok = (skw >= sw) && (skw < sw + 7);
#pragma unroll
      for (int nt = 0; nt < 14; ++nt) {
        int kh = wh0 + nt;
        bool ok = wok && (kh >= sh) && (kh < sh + 7);
        float val = ok ? S[nt][reg] * 0.125f : -1e30f;
        S[nt][reg] = val;
        mx[reg] = mx[reg] > val ? mx[reg] : val;
      }
    }
#pragma unroll
    for (int reg = 0; reg < 4; ++reg)
#pragma unroll
      for (int off = 8; off >= 1; off >>= 1) {
        float o = __shfl_xor(mx[reg], off);
        mx[reg] = mx[reg] > o ? mx[reg] : o;
      }

    // ---- exp + row sum ----
    float sm[4] = {0.f, 0.f, 0.f, 0.f};
#pragma unroll
    for (int nt = 0; nt < 14; ++nt)
#pragma unroll
      for (int reg = 0; reg < 4; ++reg) {
        float p = __expf(S[nt][reg] - mx[reg]);
        S[nt][reg] = p;
        sm[reg] += p;
      }
#pragma unroll
    for (int reg = 0; reg < 4; ++reg)
#pragma unroll
      for (int off = 8; off >= 1; off >>= 1)
        sm[reg] += __shfl_xor(sm[reg], off);

    // ---- P -> per-wave LDS region (wave-private; no barrier needed) ----
#pragma unroll
    for (int reg = 0; reg < 4; ++reg) {
      float inv = 1.f / sm[reg];
      int row = quad * 4 + reg;
#pragma unroll
      for (int nt = 0; nt < 14; ++nt)
        sbuf[wv][row][nt * 16 + n16] = (__bf16)(S[nt][reg] * inv);
    }

    __syncthreads();  // all waves done reading kwin
    // ---- coop load V window into vwin[dh][232] (key = kr*16+kc) ----
    const __bf16* vtb = vt + base;
#pragma unroll
    for (int i = 0; i < 7; ++i) {
      int c = i * 256 + tid;  // 1792 16-B chunks: c = dh*28 + kr*2 + half
      int dh = c / 28, rem = c % 28;
      int kr = rem >> 1, half = rem & 1;
      bf16x8 d = *(const bf16x8*)(vtb + (size_t)dh * 4096 +
                                  (wh0 + kr) * 64 + wc0 + half * 8);
      *(bf16x8*)&r1[dh * 232 + kr * 16 + half * 8] = d;
    }
    __syncthreads();

    // ---- PV: O[16q x 64dh] = P(16x224) . V_win(224x64), all LDS ----
    f32x4 O[4] = {{0.f, 0.f, 0.f, 0.f},
                  {0.f, 0.f, 0.f, 0.f},
                  {0.f, 0.f, 0.f, 0.f},
                  {0.f, 0.f, 0.f, 0.f}};
#pragma unroll
    for (int kt = 0; kt < 7; ++kt) {
      bf16x8 pa = *(const bf16x8*)&sbuf[wv][n16][kt * 32 + quad * 8];
      int key0 = kt * 32 + quad * 8;
#pragma unroll
      for (int ntv = 0; ntv < 4; ++ntv) {
        bf16x8 vb = *(const bf16x8*)&r1[(ntv * 16 + n16) * 232 + key0];
        O[ntv] =
            __builtin_amdgcn_mfma_f32_16x16x32_bf16(pa, vb, O[ntv], 0, 0, 0);
      }
    }

    // ---- epilogue: ao[b][s][head*64+dh] bf16 ----
    const int b = bh >> 3, head = bh & 7;
#pragma unroll
    for (int ntv = 0; ntv < 4; ++ntv)
#pragma unroll
      for (int reg = 0; reg < 4; ++reg) {
        int qi = wv * 16 + quad * 4 + reg;
        int s_q = (qh0 + (qi >> 3)) * 64 + qw0 + (qi & 7);
        int dh = ntv * 16 + n16;
        out[((size_t)(b * 4096 + s_q)) * 512 + head * 64 + dh] =
            (__bf16)O[ntv][reg];
      }
  }
}

extern "C" void kernel_launch(void* const* d_in, const int* in_sizes, int n_in,
                              void* d_out, int out_size, void* d_ws,
                              size_t ws_size, hipStream_t stream) {
  const float* x = (const float*)d_in[0];      // [2,64,64,512] fp32
  const float* w_qkv = (const float*)d_in[1];  // [1536,512] fp32
  const float* w_out = (const float*)d_in[2];  // [512,512] fp32
  float* out = (float*)d_out;                  // [2,64,64,512] fp32

  const size_t qelems = (size_t)2 * 8 * 4096 * 64;  // 4,194,304
  __bf16* q = (__bf16*)d_ws;
  __bf16* k = q + qelems;
  __bf16* vt = k + qelems;          // V transposed [bh][dh][s]
  __bf16* xb = vt + qelems;         // converted x; reused as ao
  __bf16* wqb = xb + qelems;        // converted w_qkv
  __bf16* wob = wqb + 1536 * 512;   // converted w_out
  __bf16* ao = xb;                  // attn out aliases xb (x dead after QKV)

  // Stage 0: fused fp32 -> bf16 (655360 chunks of 2x f32x4)  [x16 rep]
  cvt_all<<<dim3(2560), dim3(256), 0, stream>>>(x, w_qkv, w_out, xb, wqb, wob);

  // Stage 1: QKV GEMM: 64 i-tiles x 12 e-tiles = 768 blocks   [x4 rep]
  gemm_lds<true, 128, 4><<<dim3(768), dim3(256), 0, stream>>>(
      xb, wqb, q, k, vt, nullptr, 12);
  // Stage 2: MFMA attention: 16 bh * 64 tiles = 1024 wgs      [x6 rep]
  attn_mfma<<<dim3(1024), dim3(256), 0, stream>>>(q, k, vt, ao);
  // Stage 3: out GEMM: 64 i-tiles x 8 e-tiles = 512 blocks    [x6 rep]
  gemm_lds<false, 64, 6><<<dim3(512), dim3(256), 0, stream>>>(
      ao, wob, nullptr, nullptr, nullptr, out, 8);
}

// Round 3
// 136.130 us; speedup vs baseline: 2.6707x; 2.6707x over previous
//
#include <hip/hip_runtime.h>
#include <hip/hip_bf16.h>

// NeighbourhoodAttnBlock: B=2, H=W=64, D=512, NH=8, DH=64, KERNEL=7
// Inputs fp32; output fp32. Internal pipeline bf16 MFMA.
// R3 = R2 resubmit (R2 died to container infra failure, not kernel).
// attn latency fix (counters: MfmaUtil 7%, Occ 22%, all pipes idle ->
// latency-bound with two exposed global epochs).
//  - V window prefetched to REGISTERS at kernel start (T14 async-STAGE
//    split): V HBM latency now overlaps the K load + QK^T + softmax.
//  - K window staged via global_load_lds with PRE-SWIZZLED global source
//    (m173): same swizzled kwin layout, no reg round-trip, no ds_writes.
// Stages 0/1/3 identical to the 135.5us best kernel.

typedef __bf16 bf16x8 __attribute__((ext_vector_type(8)));
typedef __bf16 bf16x4 __attribute__((ext_vector_type(4)));
typedef float  f32x4  __attribute__((ext_vector_type(4)));

__global__ __launch_bounds__(256) void cvt_all(
    const float* __restrict__ x, const float* __restrict__ wq,
    const float* __restrict__ wo, __bf16* __restrict__ xb,
    __bf16* __restrict__ wqb, __bf16* __restrict__ wob) {
  // 655360 chunks of 2x f32x4 (32B read / 16B write per thread)
  int i = blockIdx.x * 256 + threadIdx.x;
  const float* src;
  __bf16* dst;
  int j = i;
  if (j < 524288) {
    src = x; dst = xb;
  } else if (j < 524288 + 98304) {
    j -= 524288; src = wq; dst = wqb;
  } else {
    j -= 524288 + 98304; src = wo; dst = wob;
  }
  f32x4 v0 = ((const f32x4*)src)[j * 2];
  f32x4 v1 = ((const f32x4*)src)[j * 2 + 1];
  bf16x8 o;
  o[0] = (__bf16)v0[0]; o[1] = (__bf16)v0[1];
  o[2] = (__bf16)v0[2]; o[3] = (__bf16)v0[3];
  o[4] = (__bf16)v1[0]; o[5] = (__bf16)v1[1];
  o[6] = (__bf16)v1[2]; o[7] = (__bf16)v1[3];
  ((bf16x8*)dst)[j] = o;
}

__device__ __forceinline__ void gload_lds16(const __bf16* g, __bf16* l) {
  __builtin_amdgcn_global_load_lds(
      (const __attribute__((address_space(1))) void*)g,
      (__attribute__((address_space(3))) void*)l, 16, 0, 0);
}

// C[i][e] = sum_d A[i][d] * W[e][d];  A:[M,512], W:[E,512] row-major bf16.
// 128xBN block tile, 4 waves x (64 x BN/2). BK=64 via two contiguous 32-col
// half-buffers (global_load_lds needs unpadded contiguity).
template <bool QKV, int BN>
__global__ __launch_bounds__(256, 3) void gemm_lds(
    const __bf16* __restrict__ A, const __bf16* __restrict__ W,
    __bf16* __restrict__ qo, __bf16* __restrict__ ko, __bf16* __restrict__ vo,
    float* __restrict__ co, int etiles) {
  constexpr int K = 512;
  constexpr int NT = BN / 32;
  constexpr int WHALF = BN * 32;
  __shared__ alignas(16) __bf16 Al[2 * 128 * 32];
  __shared__ alignas(16) __bf16 Wl[2 * WHALF];
  const int tid = threadIdx.x;
  const int wv = tid >> 6, lane = tid & 63;
  const int n16 = lane & 15, quad = lane >> 4;
  const int bi = blockIdx.x / etiles, be = blockIdx.x % etiles;
  const int i0 = bi << 7, e0 = be * BN;
  const int wm = (wv & 1) << 6, we = (wv >> 1) * (BN / 2);

  const int srow = (wv << 4) + (lane >> 2);
  const int scol = (lane & 3) << 3;
  const __bf16* gA = A + (size_t)(i0 + srow) * K + scol;
  const __bf16* gW = W + (size_t)(e0 + srow) * K + scol;
  const int soff = (wv << 9) + (lane << 3);

  f32x4 acc[4][NT];
#pragma unroll
  for (int a = 0; a < 4; ++a)
#pragma unroll
    for (int b = 0; b < NT; ++b) acc[a][b] = (f32x4){0.f, 0.f, 0.f, 0.f};

  for (int k0 = 0; k0 < K; k0 += 64) {
    if (k0) __syncthreads();
#pragma unroll
    for (int h = 0; h < 2; ++h) {
      gload_lds16(gA + k0 + h * 32, &Al[h * 4096 + soff]);
      gload_lds16(gA + (size_t)64 * K + k0 + h * 32,
                  &Al[h * 4096 + 64 * 32 + soff]);
      gload_lds16(gW + k0 + h * 32, &Wl[h * WHALF + soff]);
      if (BN == 128)
        gload_lds16(gW + (size_t)64 * K + k0 + h * 32,
                    &Wl[h * WHALF + 64 * 32 + soff]);
    }
    __syncthreads();

#pragma unroll
    for (int h = 0; h < 2; ++h) {
      bf16x8 af[4], wf[NT];
#pragma unroll
      for (int t = 0; t < 4; ++t)
        af[t] = *(const bf16x8*)&Al[h * 4096 + (wm + t * 16 + n16) * 32 +
                                    quad * 8];
#pragma unroll
      for (int t = 0; t < NT; ++t)
        wf[t] = *(const bf16x8*)&Wl[h * WHALF + (we + t * 16 + n16) * 32 +
                                    quad * 8];
#pragma unroll
      for (int mt = 0; mt < 4; ++mt)
#pragma unroll
        for (int nt = 0; nt < NT; ++nt)
          acc[mt][nt] = __builtin_amdgcn_mfma_f32_16x16x32_bf16(
              af[mt], wf[nt], acc[mt][nt], 0, 0, 0);
    }
  }

#pragma unroll
  for (int mt = 0; mt < 4; ++mt)
#pragma unroll
    for (int nt = 0; nt < NT; ++nt) {
      f32x4 f = acc[mt][nt];
      int e = e0 + we + nt * 16 + n16;
#pragma unroll
      for (int rg = 0; rg < 4; ++rg) {
        int i = i0 + wm + mt * 16 + quad * 4 + rg;
        float val = f[rg];
        if (QKV) {
          int t = e >> 9, head = (e >> 6) & 7, dh = e & 63;
          int b = i >> 12, s = i & 4095;
          int bh = b * 8 + head;
          if (t == 2) {
            vo[((size_t)bh * 64 + dh) * 4096 + s] = (__bf16)val;  // vt[bh][dh][s]
          } else {
            size_t off = (((size_t)bh * 4096) + s) * 64 + dh;
            ((t == 0) ? qo : ko)[off] = (__bf16)val;
          }
        } else {
          co[(size_t)i * 512 + e] = val;  // fp32 output
        }
      }
    }
}

// MFMA neighbourhood attention.
// One workgroup per (bh, 8x8 query tile).
// Phase 0: issue K-window staging via pre-swizzled global_load_lds AND
//          V-window prefetch into registers (T14): both global epochs fly
//          concurrently; only ONE exposed latency epoch remains.
// Phase 1: QK^T via ds_read_b128 (xor-swizzled kwin); softmax in regs;
//          P -> per-wave sbuf.
// Phase 2: barrier; vreg -> vwin[dh][232] LDS writes (data already here);
//          PV fully from LDS.
__global__ __launch_bounds__(256) void attn_mfma(
    const __bf16* __restrict__ q, const __bf16* __restrict__ k,
    const __bf16* __restrict__ vt, __bf16* __restrict__ out) {
  __shared__ alignas(16) __bf16 r1[14848];         // kwin / vwin[64][232]
  __shared__ alignas(16) __bf16 sbuf[4][16][232];  // per-wave P (padded)
  const int tid = threadIdx.x;
  const int wv = tid >> 6;
  const int lane = tid & 63;
  const int n16 = lane & 15, quad = lane >> 4;
  const int bh = blockIdx.x >> 6;
  const int tile = blockIdx.x & 63;
  const int qh0 = (tile >> 3) << 3, qw0 = (tile & 7) << 3;
  int wh0 = qh0 - 3; wh0 = wh0 < 0 ? 0 : (wh0 > 50 ? 50 : wh0);
  int wc0 = qw0 - 3; wc0 = wc0 < 0 ? 0 : (wc0 > 48 ? 48 : wc0);
  wc0 &= ~1;  // window covers [qw0-3, qw0+10]
  const size_t base = (size_t)bh * 4096 * 64;

  // ---- Q A-frags (fly during coop loads) ----
  const int qi_a = wv * 16 + n16;
  const int sqa = (qh0 + (qi_a >> 3)) * 64 + qw0 + (qi_a & 7);
  const __bf16* qp = q + base + (size_t)sqa * 64 + quad * 8;
  bf16x8 aq0 = *(const bf16x8*)qp;
  bf16x8 aq1 = *(const bf16x8*)(qp + 32);

  // ---- K window staging: global_load_lds, source pre-swizzled ----
  // LDS slot (kr,kc,slot) <- global (kr,kc,slot^(kc&7)); dest linear ch*16B
  // (wave-uniform base + lane*16), layout identical to old swizzled kwin.
  const __bf16* kbase = k + base;
#pragma unroll
  for (int i = 0; i < 7; ++i) {
    int ch = i * 256 + tid;           // 1792 16-B chunks
    int kr = ch >> 7, wi = ch & 127;
    int kc = wi >> 3, dh8 = wi & 7;
    gload_lds16(kbase + (size_t)((wh0 + kr) * 64 + wc0 + kc) * 64 +
                    ((dh8 ^ (kc & 7)) * 8),
                &r1[ch * 8]);
  }

  // ---- V window prefetch -> registers (T14 issue-early / write-late) ----
  bf16x8 vreg[7];
  int voff[7];
  const __bf16* vtb = vt + base;
#pragma unroll
  for (int i = 0; i < 7; ++i) {
    int c = i * 256 + tid;  // 1792 16-B chunks: c = dh*28 + kr*2 + half
    int dh = c / 28, rem = c % 28;
    int kr = rem >> 1, half = rem & 1;
    vreg[i] = *(const bf16x8*)(vtb + (size_t)dh * 4096 +
                               (wh0 + kr) * 64 + wc0 + half * 8);
    voff[i] = dh * 232 + kr * 16 + half * 8;
  }
  __syncthreads();  // drains K (and V) vmem; kwin ready

  // ---- scores from LDS ----
  f32x4 S[14];
  const int skw = wc0 + n16;
  const int sw1 = ((quad ^ (n16 & 7)) * 8);
  const int sw2 = (((4 + quad) ^ (n16 & 7)) * 8);
#pragma unroll
  for (int nt = 0; nt < 14; ++nt) {
    int key = nt * 16 + n16;
    bf16x8 b0 = *(const bf16x8*)&r1[key * 64 + sw1];
    bf16x8 b1 = *(const bf16x8*)&r1[key * 64 + sw2];
    f32x4 s = {0.f, 0.f, 0.f, 0.f};
    s = __builtin_amdgcn_mfma_f32_16x16x32_bf16(aq0, b0, s, 0, 0, 0);
    s = __builtin_amdgcn_mfma_f32_16x16x32_bf16(aq1, b1, s, 0, 0, 0);
    S[nt] = s;
  }

  // ---- exact mask + scale + row max ----
  float mx[4] = {-1e30f, -1e30f, -1e30f, -1e30f};
#pragma unroll
  for (int reg = 0; reg < 4; ++reg) {
    int qi = wv * 16 + quad * 4 + reg;
    int qh = qh0 + (qi >> 3), qw = qw0 + (qi & 7);
    int sh = qh - 3; sh = sh < 0 ? 0 : (sh > 57 ? 57 : sh);
    int sw = qw - 3; sw = sw < 0 ? 0 : (sw > 57 ? 57 : sw);
    bool wok = (skw >= sw) && (skw < sw + 7);
#pragma unroll
    for (int nt = 0; nt < 14; ++nt) {
      int kh = wh0 + nt;
      bool ok = wok && (kh >= sh) && (kh < sh + 7);
      float val = ok ? S[nt][reg] * 0.125f : -1e30f;
      S[nt][reg] = val;
      mx[reg] = mx[reg] > val ? mx[reg] : val;
    }
  }
#pragma unroll
  for (int reg = 0; reg < 4; ++reg)
#pragma unroll
    for (int off = 8; off >= 1; off >>= 1) {
      float o = __shfl_xor(mx[reg], off);
      mx[reg] = mx[reg] > o ? mx[reg] : o;
    }

  // ---- exp + row sum ----
  float sm[4] = {0.f, 0.f, 0.f, 0.f};
#pragma unroll
  for (int nt = 0; nt < 14; ++nt)
#pragma unroll
    for (int reg = 0; reg < 4; ++reg) {
      float p = __expf(S[nt][reg] - mx[reg]);
      S[nt][reg] = p;
      sm[reg] += p;
    }
#pragma unroll
  for (int reg = 0; reg < 4; ++reg)
#pragma unroll
    for (int off = 8; off >= 1; off >>= 1) sm[reg] += __shfl_xor(sm[reg], off);

  // ---- P -> per-wave LDS region (wave-private; no barrier needed) ----
#pragma unroll
  for (int reg = 0; reg < 4; ++reg) {
    float inv = 1.f / sm[reg];
    int row = quad * 4 + reg;
#pragma unroll
    for (int nt = 0; nt < 14; ++nt)
      sbuf[wv][row][nt * 16 + n16] = (__bf16)(S[nt][reg] * inv);
  }

  __syncthreads();  // all waves done reading kwin
  // ---- V window: registers -> vwin[dh][232] (data already on-chip) ----
#pragma unroll
  for (int i = 0; i < 7; ++i) *(bf16x8*)&r1[voff[i]] = vreg[i];
  __syncthreads();

  // ---- PV: O[16q x 64dh] = P(16x224) . V_win(224x64), all LDS ----
  f32x4 O[4] = {{0.f, 0.f, 0.f, 0.f},
                {0.f, 0.f, 0.f, 0.f},
                {0.f, 0.f, 0.f, 0.f},
                {0.f, 0.f, 0.f, 0.f}};
#pragma unroll
  for (int kt = 0; kt < 7; ++kt) {
    bf16x8 pa = *(const bf16x8*)&sbuf[wv][n16][kt * 32 + quad * 8];
    int key0 = kt * 32 + quad * 8;
#pragma unroll
    for (int ntv = 0; ntv < 4; ++ntv) {
      bf16x8 vb = *(const bf16x8*)&r1[(ntv * 16 + n16) * 232 + key0];
      O[ntv] = __builtin_amdgcn_mfma_f32_16x16x32_bf16(pa, vb, O[ntv], 0, 0, 0);
    }
  }

  // ---- epilogue: ao[b][s][head*64+dh] bf16 ----
  const int b = bh >> 3, head = bh & 7;
#pragma unroll
  for (int ntv = 0; ntv < 4; ++ntv)
#pragma unroll
    for (int reg = 0; reg < 4; ++reg) {
      int qi = wv * 16 + quad * 4 + reg;
      int s_q = (qh0 + (qi >> 3)) * 64 + qw0 + (qi & 7);
      int dh = ntv * 16 + n16;
      out[((size_t)(b * 4096 + s_q)) * 512 + head * 64 + dh] =
          (__bf16)O[ntv][reg];
    }
}

extern "C" void kernel_launch(void* const* d_in, const int* in_sizes, int n_in,
                              void* d_out, int out_size, void* d_ws,
                              size_t ws_size, hipStream_t stream) {
  const float* x = (const float*)d_in[0];      // [2,64,64,512] fp32
  const float* w_qkv = (const float*)d_in[1];  // [1536,512] fp32
  const float* w_out = (const float*)d_in[2];  // [512,512] fp32
  float* out = (float*)d_out;                  // [2,64,64,512] fp32

  const size_t qelems = (size_t)2 * 8 * 4096 * 64;  // 4,194,304
  __bf16* q = (__bf16*)d_ws;
  __bf16* k = q + qelems;
  __bf16* vt = k + qelems;          // V transposed [bh][dh][s]
  __bf16* xb = vt + qelems;         // converted x; reused as ao
  __bf16* wqb = xb + qelems;        // converted w_qkv
  __bf16* wob = wqb + 1536 * 512;   // converted w_out
  __bf16* ao = xb;                  // attn out aliases xb (x dead after QKV)

  // Stage 0: fused fp32 -> bf16 (655360 chunks of 2x f32x4)
  cvt_all<<<dim3(2560), dim3(256), 0, stream>>>(x, w_qkv, w_out, xb, wqb, wob);

  // Stage 1: QKV GEMM: 64 i-tiles x 12 e-tiles = 768 blocks (3/CU)
  gemm_lds<true, 128><<<dim3(768), dim3(256), 0, stream>>>(
      xb, wqb, q, k, vt, nullptr, 12);
  // Stage 2: MFMA attention: 16 bh * 64 tiles = 1024 workgroups
  attn_mfma<<<dim3(1024), dim3(256), 0, stream>>>(q, k, vt, ao);
  // Stage 3: out GEMM: 64 i-tiles x 8 e-tiles = 512 blocks
  gemm_lds<false, 64><<<dim3(512), dim3(256), 0, stream>>>(
      ao, wob, nullptr, nullptr, nullptr, out, 8);
}

// Round 4
// 130.968 us; speedup vs baseline: 2.7759x; 1.0394x over previous
//
#include <hip/hip_runtime.h>
#include <hip/hip_bf16.h>

// NeighbourhoodAttnBlock: B=2, H=W=64, D=512, NH=8, DH=64, KERNEL=7
// Inputs fp32; output fp32. Internal pipeline bf16 MFMA.
// R4: attn occupancy fix. R1 counters: MfmaUtil 7%, VALU 32%, Occ 22%
// (LDS 59.4KB -> 2 blocks/CU; grid has 4 wgs/CU -> 2 serialized rounds).
// sbuf (29.7KB P-transpose buffer) ELIMINATED via swapped QK^T:
//   mfma(K,Q) instead of mfma(Q,K) -> lane holds S^T[key=quad*4+reg][q=n16]
//   (A/B frags have identical lane layouts, so swap = argument swap only).
//   - softmax: one q per lane; row-reduce = 2 shfl_xor (16,32).
//   - mask: per-lane row-range lo..lo+7 + 4 col bools (VALU diet).
//   - 0.125 scale folded into q store in QKV epilogue (pow2 -> exact).
//   - PV A-frag gathered in-register per kt via 8 shfl (quad exchange);
//     P never touches LDS.
// LDS 59392 -> 29696 B -> all 4 wgs/CU co-resident.
// Stages 0/1/3 unchanged (gemm: only the q*0.125 fold).

typedef __bf16 bf16x8 __attribute__((ext_vector_type(8)));
typedef __bf16 bf16x4 __attribute__((ext_vector_type(4)));
typedef __bf16 bf16x2 __attribute__((ext_vector_type(2)));
typedef float  f32x4  __attribute__((ext_vector_type(4)));
typedef int    i32x4  __attribute__((ext_vector_type(4)));

__global__ __launch_bounds__(256) void cvt_all(
    const float* __restrict__ x, const float* __restrict__ wq,
    const float* __restrict__ wo, __bf16* __restrict__ xb,
    __bf16* __restrict__ wqb, __bf16* __restrict__ wob) {
  // 655360 chunks of 2x f32x4 (32B read / 16B write per thread)
  int i = blockIdx.x * 256 + threadIdx.x;
  const float* src;
  __bf16* dst;
  int j = i;
  if (j < 524288) {
    src = x; dst = xb;
  } else if (j < 524288 + 98304) {
    j -= 524288; src = wq; dst = wqb;
  } else {
    j -= 524288 + 98304; src = wo; dst = wob;
  }
  f32x4 v0 = ((const f32x4*)src)[j * 2];
  f32x4 v1 = ((const f32x4*)src)[j * 2 + 1];
  bf16x8 o;
  o[0] = (__bf16)v0[0]; o[1] = (__bf16)v0[1];
  o[2] = (__bf16)v0[2]; o[3] = (__bf16)v0[3];
  o[4] = (__bf16)v1[0]; o[5] = (__bf16)v1[1];
  o[6] = (__bf16)v1[2]; o[7] = (__bf16)v1[3];
  ((bf16x8*)dst)[j] = o;
}

__device__ __forceinline__ void gload_lds16(const __bf16* g, __bf16* l) {
  __builtin_amdgcn_global_load_lds(
      (const __attribute__((address_space(1))) void*)g,
      (__attribute__((address_space(3))) void*)l, 16, 0, 0);
}

// C[i][e] = sum_d A[i][d] * W[e][d];  A:[M,512], W:[E,512] row-major bf16.
// 128xBN block tile, 4 waves x (64 x BN/2). BK=64 via two contiguous 32-col
// half-buffers (global_load_lds needs unpadded contiguity).
template <bool QKV, int BN>
__global__ __launch_bounds__(256, 3) void gemm_lds(
    const __bf16* __restrict__ A, const __bf16* __restrict__ W,
    __bf16* __restrict__ qo, __bf16* __restrict__ ko, __bf16* __restrict__ vo,
    float* __restrict__ co, int etiles) {
  constexpr int K = 512;
  constexpr int NT = BN / 32;
  constexpr int WHALF = BN * 32;
  __shared__ alignas(16) __bf16 Al[2 * 128 * 32];
  __shared__ alignas(16) __bf16 Wl[2 * WHALF];
  const int tid = threadIdx.x;
  const int wv = tid >> 6, lane = tid & 63;
  const int n16 = lane & 15, quad = lane >> 4;
  const int bi = blockIdx.x / etiles, be = blockIdx.x % etiles;
  const int i0 = bi << 7, e0 = be * BN;
  const int wm = (wv & 1) << 6, we = (wv >> 1) * (BN / 2);

  const int srow = (wv << 4) + (lane >> 2);
  const int scol = (lane & 3) << 3;
  const __bf16* gA = A + (size_t)(i0 + srow) * K + scol;
  const __bf16* gW = W + (size_t)(e0 + srow) * K + scol;
  const int soff = (wv << 9) + (lane << 3);

  f32x4 acc[4][NT];
#pragma unroll
  for (int a = 0; a < 4; ++a)
#pragma unroll
    for (int b = 0; b < NT; ++b) acc[a][b] = (f32x4){0.f, 0.f, 0.f, 0.f};

  for (int k0 = 0; k0 < K; k0 += 64) {
    if (k0) __syncthreads();
#pragma unroll
    for (int h = 0; h < 2; ++h) {
      gload_lds16(gA + k0 + h * 32, &Al[h * 4096 + soff]);
      gload_lds16(gA + (size_t)64 * K + k0 + h * 32,
                  &Al[h * 4096 + 64 * 32 + soff]);
      gload_lds16(gW + k0 + h * 32, &Wl[h * WHALF + soff]);
      if (BN == 128)
        gload_lds16(gW + (size_t)64 * K + k0 + h * 32,
                    &Wl[h * WHALF + 64 * 32 + soff]);
    }
    __syncthreads();

#pragma unroll
    for (int h = 0; h < 2; ++h) {
      bf16x8 af[4], wf[NT];
#pragma unroll
      for (int t = 0; t < 4; ++t)
        af[t] = *(const bf16x8*)&Al[h * 4096 + (wm + t * 16 + n16) * 32 +
                                    quad * 8];
#pragma unroll
      for (int t = 0; t < NT; ++t)
        wf[t] = *(const bf16x8*)&Wl[h * WHALF + (we + t * 16 + n16) * 32 +
                                    quad * 8];
#pragma unroll
      for (int mt = 0; mt < 4; ++mt)
#pragma unroll
        for (int nt = 0; nt < NT; ++nt)
          acc[mt][nt] = __builtin_amdgcn_mfma_f32_16x16x32_bf16(
              af[mt], wf[nt], acc[mt][nt], 0, 0, 0);
    }
  }

#pragma unroll
  for (int mt = 0; mt < 4; ++mt)
#pragma unroll
    for (int nt = 0; nt < NT; ++nt) {
      f32x4 f = acc[mt][nt];
      int e = e0 + we + nt * 16 + n16;
#pragma unroll
      for (int rg = 0; rg < 4; ++rg) {
        int i = i0 + wm + mt * 16 + quad * 4 + rg;
        float val = f[rg];
        if (QKV) {
          int t = e >> 9, head = (e >> 6) & 7, dh = e & 63;
          int b = i >> 12, s = i & 4095;
          int bh = b * 8 + head;
          if (t == 2) {
            vo[((size_t)bh * 64 + dh) * 4096 + s] = (__bf16)val;  // vt[bh][dh][s]
          } else {
            size_t off = (((size_t)bh * 4096) + s) * 64 + dh;
            // fold attn scale 1/8 into q (exact: power-of-two)
            float sval = (t == 0) ? val * 0.125f : val;
            ((t == 0) ? qo : ko)[off] = (__bf16)sval;
          }
        } else {
          co[(size_t)i * 512 + e] = val;  // fp32 output
        }
      }
    }
}

// MFMA neighbourhood attention, swapped-QK^T / in-register-P version.
// One workgroup per (bh, 8x8 query tile). LDS = kwin/vwin only (29.7 KB).
// Phase 1: K window -> LDS (pre-swizzled gload_lds); S^T = mfma(K,Q);
//          per-lane mask + softmax (one q per lane); P packed to bf16 regs.
// Phase 2: barrier; V window -> LDS [dh][232]; PV with per-kt in-register
//          P gather (8 shfl quad-exchange) -> mfma(pa, vb).
__global__ __launch_bounds__(256, 4) void attn_mfma(
    const __bf16* __restrict__ q, const __bf16* __restrict__ k,
    const __bf16* __restrict__ vt, __bf16* __restrict__ out) {
  __shared__ alignas(16) __bf16 r1[14848];  // kwin / vwin[64][232]
  const int tid = threadIdx.x;
  const int wv = tid >> 6;
  const int lane = tid & 63;
  const int n16 = lane & 15, quad = lane >> 4;
  const int bh = blockIdx.x >> 6;
  const int tile = blockIdx.x & 63;
  const int qh0 = (tile >> 3) << 3, qw0 = (tile & 7) << 3;
  int wh0 = qh0 - 3; wh0 = wh0 < 0 ? 0 : (wh0 > 50 ? 50 : wh0);
  int wc0 = qw0 - 3; wc0 = wc0 < 0 ? 0 : (wc0 > 48 ? 48 : wc0);
  wc0 &= ~1;  // window covers [qw0-3, qw0+10]
  const size_t base = (size_t)bh * 4096 * 64;

  // ---- Q frags (B-operand of swapped QK^T; layout identical to A-frag) ----
  const int qi = wv * 16 + n16;  // this lane's query (softmax row)
  const int sq = (qh0 + (qi >> 3)) * 64 + qw0 + (qi & 7);
  const __bf16* qp = q + base + (size_t)sq * 64 + quad * 8;
  bf16x8 bq0 = *(const bf16x8*)qp;
  bf16x8 bq1 = *(const bf16x8*)(qp + 32);

  // ---- K window staging: global_load_lds, source pre-swizzled (R3-verified)
  const __bf16* kbase = k + base;
#pragma unroll
  for (int i = 0; i < 7; ++i) {
    int ch = i * 256 + tid;           // 1792 16-B chunks
    int kr = ch >> 7, wi = ch & 127;
    int kc = wi >> 3, dh8 = wi & 7;
    gload_lds16(kbase + (size_t)((wh0 + kr) * 64 + wc0 + kc) * 64 +
                    ((dh8 ^ (kc & 7)) * 8),
                &r1[ch * 8]);
  }
  __syncthreads();

  // ---- swapped QK^T: S[nt] = S^T tile; lane = [key=nt*16+quad*4+reg][q=n16]
  f32x4 S[14];
  const int sw1 = ((quad ^ (n16 & 7)) * 8);
  const int sw2 = (((4 + quad) ^ (n16 & 7)) * 8);
#pragma unroll
  for (int nt = 0; nt < 14; ++nt) {
    int key = nt * 16 + n16;
    bf16x8 kf0 = *(const bf16x8*)&r1[key * 64 + sw1];
    bf16x8 kf1 = *(const bf16x8*)&r1[key * 64 + sw2];
    f32x4 s = {0.f, 0.f, 0.f, 0.f};
    s = __builtin_amdgcn_mfma_f32_16x16x32_bf16(kf0, bq0, s, 0, 0, 0);
    s = __builtin_amdgcn_mfma_f32_16x16x32_bf16(kf1, bq1, s, 0, 0, 0);
    S[nt] = s;
  }

  // ---- mask (scale already folded into q): one query per lane ----
  const int qh = qh0 + (qi >> 3), qw = qw0 + (qi & 7);
  int sh = qh - 3; sh = sh < 0 ? 0 : (sh > 57 ? 57 : sh);
  int sw = qw - 3; sw = sw < 0 ? 0 : (sw > 57 ? 57 : sw);
  const int lo = sh - wh0;  // valid key-rows: nt in [lo, lo+7)
  bool wok[4];
#pragma unroll
  for (int reg = 0; reg < 4; ++reg) {
    int kw = wc0 + quad * 4 + reg;  // fixed key col per (lane,reg)
    wok[reg] = (kw >= sw) && (kw < sw + 7);
  }
  float mx[4] = {-1e30f, -1e30f, -1e30f, -1e30f};
#pragma unroll
  for (int nt = 0; nt < 14; ++nt) {
    bool rok = (unsigned)(nt - lo) < 7u;
#pragma unroll
    for (int reg = 0; reg < 4; ++reg) {
      float val = (rok && wok[reg]) ? S[nt][reg] : -1e30f;
      S[nt][reg] = val;
      mx[reg] = mx[reg] > val ? mx[reg] : val;
    }
  }
  float m = fmaxf(fmaxf(mx[0], mx[1]), fmaxf(mx[2], mx[3]));
  m = fmaxf(m, __shfl_xor(m, 16));
  m = fmaxf(m, __shfl_xor(m, 32));

  // ---- exp + row sum (row = this lane's q; reduce across quads) ----
  float sm[4] = {0.f, 0.f, 0.f, 0.f};
#pragma unroll
  for (int nt = 0; nt < 14; ++nt)
#pragma unroll
    for (int reg = 0; reg < 4; ++reg) {
      float p = __expf(S[nt][reg] - m);
      S[nt][reg] = p;
      sm[reg] += p;
    }
  float ssum = (sm[0] + sm[1]) + (sm[2] + sm[3]);
  ssum += __shfl_xor(ssum, 16);
  ssum += __shfl_xor(ssum, 32);
  const float inv = 1.f / ssum;

  // ---- pack normalized P in regs: plo=(reg0,reg1), phi=(reg2,reg3) ----
  int plo[14], phi[14];
#pragma unroll
  for (int nt = 0; nt < 14; ++nt) {
    bf16x2 a = {(__bf16)(S[nt][0] * inv), (__bf16)(S[nt][1] * inv)};
    bf16x2 b = {(__bf16)(S[nt][2] * inv), (__bf16)(S[nt][3] * inv)};
    plo[nt] = __builtin_bit_cast(int, a);
    phi[nt] = __builtin_bit_cast(int, b);
  }

  __syncthreads();  // all waves done reading kwin
  // ---- V coop load: global -> vwin[dh][232] (key = kr*16+kc) ----
  const __bf16* vtb = vt + base;
#pragma unroll
  for (int i = 0; i < 7; ++i) {
    int c = i * 256 + tid;  // 1792 16-B chunks: c = dh*28 + kr*2 + half
    int dh = c / 28, rem = c % 28;
    int kr = rem >> 1, half = rem & 1;
    bf16x8 d = *(const bf16x8*)(vtb + (size_t)dh * 4096 +
                                (wh0 + kr) * 64 + wc0 + half * 8);
    *(bf16x8*)&r1[dh * 232 + kr * 16 + half * 8] = d;
  }
  __syncthreads();

  // ---- PV: O[16q x 64dh]; A-frag gathered in-register per kt ----
  // pa elem j = P[key=kt*32+quad*8+j][q=n16]. Source lane holds key-col
  // quad_s*4+reg at q=n16 -> gather from lanes s0=((quad&1)*2)*16+n16 and
  // s1=s0+16; key-row parity: quads 0,1 need nt=2kt, quads 2,3 nt=2kt+1.
  f32x4 O[4] = {{0.f, 0.f, 0.f, 0.f},
                {0.f, 0.f, 0.f, 0.f},
                {0.f, 0.f, 0.f, 0.f},
                {0.f, 0.f, 0.f, 0.f}};
  const int s0 = ((quad & 1) << 5) + n16;
  const int s1 = s0 + 16;
  const bool hiq = quad >= 2;
#pragma unroll
  for (int kt = 0; kt < 7; ++kt) {
    const int nA = 2 * kt, nB = 2 * kt + 1;
    int a0 = __shfl(plo[nA], s0), a1 = __shfl(phi[nA], s0);
    int a2 = __shfl(plo[nA], s1), a3 = __shfl(phi[nA], s1);
    int b0 = __shfl(plo[nB], s0), b1 = __shfl(phi[nB], s0);
    int b2 = __shfl(plo[nB], s1), b3 = __shfl(phi[nB], s1);
    i32x4 pu = {hiq ? b0 : a0, hiq ? b1 : a1, hiq ? b2 : a2, hiq ? b3 : a3};
    bf16x8 pa = __builtin_bit_cast(bf16x8, pu);
    const int key0 = kt * 32 + quad * 8;
#pragma unroll
    for (int ntv = 0; ntv < 4; ++ntv) {
      bf16x8 vb = *(const bf16x8*)&r1[(ntv * 16 + n16) * 232 + key0];
      O[ntv] = __builtin_amdgcn_mfma_f32_16x16x32_bf16(pa, vb, O[ntv], 0, 0, 0);
    }
  }

  // ---- epilogue: ao[b][s][head*64+dh] bf16 (O rows: q=quad*4+reg) ----
  const int b = bh >> 3, head = bh & 7;
#pragma unroll
  for (int ntv = 0; ntv < 4; ++ntv)
#pragma unroll
    for (int reg = 0; reg < 4; ++reg) {
      int qe = wv * 16 + quad * 4 + reg;
      int s_q = (qh0 + (qe >> 3)) * 64 + qw0 + (qe & 7);
      int dh = ntv * 16 + n16;
      out[((size_t)(b * 4096 + s_q)) * 512 + head * 64 + dh] =
          (__bf16)O[ntv][reg];
    }
}

extern "C" void kernel_launch(void* const* d_in, const int* in_sizes, int n_in,
                              void* d_out, int out_size, void* d_ws,
                              size_t ws_size, hipStream_t stream) {
  const float* x = (const float*)d_in[0];      // [2,64,64,512] fp32
  const float* w_qkv = (const float*)d_in[1];  // [1536,512] fp32
  const float* w_out = (const float*)d_in[2];  // [512,512] fp32
  float* out = (float*)d_out;                  // [2,64,64,512] fp32

  const size_t qelems = (size_t)2 * 8 * 4096 * 64;  // 4,194,304
  __bf16* q = (__bf16*)d_ws;
  __bf16* k = q + qelems;
  __bf16* vt = k + qelems;          // V transposed [bh][dh][s]
  __bf16* xb = vt + qelems;         // converted x; reused as ao
  __bf16* wqb = xb + qelems;        // converted w_qkv
  __bf16* wob = wqb + 1536 * 512;   // converted w_out
  __bf16* ao = xb;                  // attn out aliases xb (x dead after QKV)

  // Stage 0: fused fp32 -> bf16 (655360 chunks of 2x f32x4)
  cvt_all<<<dim3(2560), dim3(256), 0, stream>>>(x, w_qkv, w_out, xb, wqb, wob);

  // Stage 1: QKV GEMM: 64 i-tiles x 12 e-tiles = 768 blocks (3/CU)
  gemm_lds<true, 128><<<dim3(768), dim3(256), 0, stream>>>(
      xb, wqb, q, k, vt, nullptr, 12);
  // Stage 2: MFMA attention: 16 bh * 64 tiles = 1024 workgroups (4/CU)
  attn_mfma<<<dim3(1024), dim3(256), 0, stream>>>(q, k, vt, ao);
  // Stage 3: out GEMM: 64 i-tiles x 8 e-tiles = 512 blocks
  gemm_lds<false, 64><<<dim3(512), dim3(256), 0, stream>>>(
      ao, wob, nullptr, nullptr, nullptr, out, 8);
}

// Round 5
// 121.012 us; speedup vs baseline: 3.0043x; 1.0823x over previous
//
#include <hip/hip_runtime.h>
#include <hip/hip_bf16.h>

// NeighbourhoodAttnBlock: B=2, H=W=64, D=512, NH=8, DH=64, KERNEL=7
// Inputs fp32; output fp32. Internal pipeline bf16 MFMA.
// R5: XCD-locality + attn register diet.
//  - T1 XCD-aware chunked swizzle on ALL grids (1024/768/512, all %8==0,
//    bijective): neighbourhood windows of adjacent query tiles overlap
//    ~75%; chunking gives each XCD 2 whole bh (3.1MB q+k+vt < 4MB L2) so
//    window re-reads become L2 hits instead of HBM re-fetch (R1: attn
//    fetched 45MB/rep vs 25MB logical).
//  - attn: P packed UNNORMALIZED (exp<=1); 1/ssum applied to O after PV
//    via 4 shfl (exact f32) -> shorter S liveness under the (256,4) cap.
// R4 heritage: swapped QK^T (S^T in regs), no sbuf, LDS 29.7KB, 4 wg/CU,
// scale folded into q store; pre-swizzled gload_lds K staging.

typedef __bf16 bf16x8 __attribute__((ext_vector_type(8)));
typedef __bf16 bf16x4 __attribute__((ext_vector_type(4)));
typedef __bf16 bf16x2 __attribute__((ext_vector_type(2)));
typedef float  f32x4  __attribute__((ext_vector_type(4)));
typedef int    i32x4  __attribute__((ext_vector_type(4)));

__global__ __launch_bounds__(256) void cvt_all(
    const float* __restrict__ x, const float* __restrict__ wq,
    const float* __restrict__ wo, __bf16* __restrict__ xb,
    __bf16* __restrict__ wqb, __bf16* __restrict__ wob) {
  // 655360 chunks of 2x f32x4 (32B read / 16B write per thread)
  int i = blockIdx.x * 256 + threadIdx.x;
  const float* src;
  __bf16* dst;
  int j = i;
  if (j < 524288) {
    src = x; dst = xb;
  } else if (j < 524288 + 98304) {
    j -= 524288; src = wq; dst = wqb;
  } else {
    j -= 524288 + 98304; src = wo; dst = wob;
  }
  f32x4 v0 = ((const f32x4*)src)[j * 2];
  f32x4 v1 = ((const f32x4*)src)[j * 2 + 1];
  bf16x8 o;
  o[0] = (__bf16)v0[0]; o[1] = (__bf16)v0[1];
  o[2] = (__bf16)v0[2]; o[3] = (__bf16)v0[3];
  o[4] = (__bf16)v1[0]; o[5] = (__bf16)v1[1];
  o[6] = (__bf16)v1[2]; o[7] = (__bf16)v1[3];
  ((bf16x8*)dst)[j] = o;
}

__device__ __forceinline__ void gload_lds16(const __bf16* g, __bf16* l) {
  __builtin_amdgcn_global_load_lds(
      (const __attribute__((address_space(1))) void*)g,
      (__attribute__((address_space(3))) void*)l, 16, 0, 0);
}

// C[i][e] = sum_d A[i][d] * W[e][d];  A:[M,512], W:[E,512] row-major bf16.
// 128xBN block tile, 4 waves x (64 x BN/2). BK=64 via two contiguous 32-col
// half-buffers (global_load_lds needs unpadded contiguity).
template <bool QKV, int BN>
__global__ __launch_bounds__(256, 3) void gemm_lds(
    const __bf16* __restrict__ A, const __bf16* __restrict__ W,
    __bf16* __restrict__ qo, __bf16* __restrict__ ko, __bf16* __restrict__ vo,
    float* __restrict__ co, int etiles) {
  constexpr int K = 512;
  constexpr int NT = BN / 32;
  constexpr int WHALF = BN * 32;
  __shared__ alignas(16) __bf16 Al[2 * 128 * 32];
  __shared__ alignas(16) __bf16 Wl[2 * WHALF];
  const int tid = threadIdx.x;
  const int wv = tid >> 6, lane = tid & 63;
  const int n16 = lane & 15, quad = lane >> 4;
  // T1 XCD chunked swizzle (gridDim.x % 8 == 0 -> bijective):
  // each XCD gets a contiguous chunk of tiles -> A-panels + W fit its L2.
  const int nper = (int)gridDim.x >> 3;
  const int wg = (blockIdx.x & 7) * nper + (blockIdx.x >> 3);
  const int bi = wg / etiles, be = wg % etiles;
  const int i0 = bi << 7, e0 = be * BN;
  const int wm = (wv & 1) << 6, we = (wv >> 1) * (BN / 2);

  const int srow = (wv << 4) + (lane >> 2);
  const int scol = (lane & 3) << 3;
  const __bf16* gA = A + (size_t)(i0 + srow) * K + scol;
  const __bf16* gW = W + (size_t)(e0 + srow) * K + scol;
  const int soff = (wv << 9) + (lane << 3);

  f32x4 acc[4][NT];
#pragma unroll
  for (int a = 0; a < 4; ++a)
#pragma unroll
    for (int b = 0; b < NT; ++b) acc[a][b] = (f32x4){0.f, 0.f, 0.f, 0.f};

  for (int k0 = 0; k0 < K; k0 += 64) {
    if (k0) __syncthreads();
#pragma unroll
    for (int h = 0; h < 2; ++h) {
      gload_lds16(gA + k0 + h * 32, &Al[h * 4096 + soff]);
      gload_lds16(gA + (size_t)64 * K + k0 + h * 32,
                  &Al[h * 4096 + 64 * 32 + soff]);
      gload_lds16(gW + k0 + h * 32, &Wl[h * WHALF + soff]);
      if (BN == 128)
        gload_lds16(gW + (size_t)64 * K + k0 + h * 32,
                    &Wl[h * WHALF + 64 * 32 + soff]);
    }
    __syncthreads();

#pragma unroll
    for (int h = 0; h < 2; ++h) {
      bf16x8 af[4], wf[NT];
#pragma unroll
      for (int t = 0; t < 4; ++t)
        af[t] = *(const bf16x8*)&Al[h * 4096 + (wm + t * 16 + n16) * 32 +
                                    quad * 8];
#pragma unroll
      for (int t = 0; t < NT; ++t)
        wf[t] = *(const bf16x8*)&Wl[h * WHALF + (we + t * 16 + n16) * 32 +
                                    quad * 8];
#pragma unroll
      for (int mt = 0; mt < 4; ++mt)
#pragma unroll
        for (int nt = 0; nt < NT; ++nt)
          acc[mt][nt] = __builtin_amdgcn_mfma_f32_16x16x32_bf16(
              af[mt], wf[nt], acc[mt][nt], 0, 0, 0);
    }
  }

#pragma unroll
  for (int mt = 0; mt < 4; ++mt)
#pragma unroll
    for (int nt = 0; nt < NT; ++nt) {
      f32x4 f = acc[mt][nt];
      int e = e0 + we + nt * 16 + n16;
#pragma unroll
      for (int rg = 0; rg < 4; ++rg) {
        int i = i0 + wm + mt * 16 + quad * 4 + rg;
        float val = f[rg];
        if (QKV) {
          int t = e >> 9, head = (e >> 6) & 7, dh = e & 63;
          int b = i >> 12, s = i & 4095;
          int bh = b * 8 + head;
          if (t == 2) {
            vo[((size_t)bh * 64 + dh) * 4096 + s] = (__bf16)val;  // vt[bh][dh][s]
          } else {
            size_t off = (((size_t)bh * 4096) + s) * 64 + dh;
            // fold attn scale 1/8 into q (exact: power-of-two)
            float sval = (t == 0) ? val * 0.125f : val;
            ((t == 0) ? qo : ko)[off] = (__bf16)sval;
          }
        } else {
          co[(size_t)i * 512 + e] = val;  // fp32 output
        }
      }
    }
}

// MFMA neighbourhood attention, swapped-QK^T / in-register-P version.
// One workgroup per (bh, 8x8 query tile). LDS = kwin/vwin only (29.7 KB).
// Phase 1: K window -> LDS (pre-swizzled gload_lds); S^T = mfma(K,Q);
//          per-lane mask + softmax (one q per lane); P packed UNNORMALIZED
//          to bf16 regs (exp <= 1); 1/ssum applied to O after PV.
// Phase 2: barrier; V window -> LDS [dh][232]; PV with per-kt in-register
//          P gather (8 shfl quad-exchange) -> mfma(pa, vb).
__global__ __launch_bounds__(256, 4) void attn_mfma(
    const __bf16* __restrict__ q, const __bf16* __restrict__ k,
    const __bf16* __restrict__ vt, __bf16* __restrict__ out) {
  __shared__ alignas(16) __bf16 r1[14848];  // kwin / vwin[64][232]
  const int tid = threadIdx.x;
  const int wv = tid >> 6;
  const int lane = tid & 63;
  const int n16 = lane & 15, quad = lane >> 4;
  // T1 XCD chunked swizzle: 1024 wgs -> each XCD owns 128 contiguous wgs
  // = 2 whole bh (q+k+vt = 3.1MB < 4MB L2): window overlap re-reads hit L2.
  const int wg = ((blockIdx.x & 7) << 7) + (blockIdx.x >> 3);
  const int bh = wg >> 6;
  const int tile = wg & 63;
  const int qh0 = (tile >> 3) << 3, qw0 = (tile & 7) << 3;
  int wh0 = qh0 - 3; wh0 = wh0 < 0 ? 0 : (wh0 > 50 ? 50 : wh0);
  int wc0 = qw0 - 3; wc0 = wc0 < 0 ? 0 : (wc0 > 48 ? 48 : wc0);
  wc0 &= ~1;  // window covers [qw0-3, qw0+10]
  const size_t base = (size_t)bh * 4096 * 64;

  // ---- Q frags (B-operand of swapped QK^T; layout identical to A-frag) ----
  const int qi = wv * 16 + n16;  // this lane's query (softmax row)
  const int sq = (qh0 + (qi >> 3)) * 64 + qw0 + (qi & 7);
  const __bf16* qp = q + base + (size_t)sq * 64 + quad * 8;
  bf16x8 bq0 = *(const bf16x8*)qp;
  bf16x8 bq1 = *(const bf16x8*)(qp + 32);

  // ---- K window staging: global_load_lds, source pre-swizzled (R3-verified)
  const __bf16* kbase = k + base;
#pragma unroll
  for (int i = 0; i < 7; ++i) {
    int ch = i * 256 + tid;           // 1792 16-B chunks
    int kr = ch >> 7, wi = ch & 127;
    int kc = wi >> 3, dh8 = wi & 7;
    gload_lds16(kbase + (size_t)((wh0 + kr) * 64 + wc0 + kc) * 64 +
                    ((dh8 ^ (kc & 7)) * 8),
                &r1[ch * 8]);
  }
  __syncthreads();

  // ---- swapped QK^T: S[nt] = S^T tile; lane = [key=nt*16+quad*4+reg][q=n16]
  f32x4 S[14];
  const int sw1 = ((quad ^ (n16 & 7)) * 8);
  const int sw2 = (((4 + quad) ^ (n16 & 7)) * 8);
#pragma unroll
  for (int nt = 0; nt < 14; ++nt) {
    int key = nt * 16 + n16;
    bf16x8 kf0 = *(const bf16x8*)&r1[key * 64 + sw1];
    bf16x8 kf1 = *(const bf16x8*)&r1[key * 64 + sw2];
    f32x4 s = {0.f, 0.f, 0.f, 0.f};
    s = __builtin_amdgcn_mfma_f32_16x16x32_bf16(kf0, bq0, s, 0, 0, 0);
    s = __builtin_amdgcn_mfma_f32_16x16x32_bf16(kf1, bq1, s, 0, 0, 0);
    S[nt] = s;
  }

  // ---- mask (scale already folded into q): one query per lane ----
  const int qh = qh0 + (qi >> 3), qw = qw0 + (qi & 7);
  int sh = qh - 3; sh = sh < 0 ? 0 : (sh > 57 ? 57 : sh);
  int sw = qw - 3; sw = sw < 0 ? 0 : (sw > 57 ? 57 : sw);
  const int lo = sh - wh0;  // valid key-rows: nt in [lo, lo+7)
  bool wok[4];
#pragma unroll
  for (int reg = 0; reg < 4; ++reg) {
    int kw = wc0 + quad * 4 + reg;  // fixed key col per (lane,reg)
    wok[reg] = (kw >= sw) && (kw < sw + 7);
  }
  float mx[4] = {-1e30f, -1e30f, -1e30f, -1e30f};
#pragma unroll
  for (int nt = 0; nt < 14; ++nt) {
    bool rok = (unsigned)(nt - lo) < 7u;
#pragma unroll
    for (int reg = 0; reg < 4; ++reg) {
      float val = (rok && wok[reg]) ? S[nt][reg] : -1e30f;
      S[nt][reg] = val;
      mx[reg] = mx[reg] > val ? mx[reg] : val;
    }
  }
  float m = fmaxf(fmaxf(mx[0], mx[1]), fmaxf(mx[2], mx[3]));
  m = fmaxf(m, __shfl_xor(m, 16));
  m = fmaxf(m, __shfl_xor(m, 32));

  // ---- exp + row sum; pack UNNORMALIZED P (exp <= 1, bf16-safe) ----
  int plo[14], phi[14];
  float sm[4] = {0.f, 0.f, 0.f, 0.f};
#pragma unroll
  for (int nt = 0; nt < 14; ++nt) {
    float p0 = __expf(S[nt][0] - m);
    float p1 = __expf(S[nt][1] - m);
    float p2 = __expf(S[nt][2] - m);
    float p3 = __expf(S[nt][3] - m);
    sm[0] += p0; sm[1] += p1; sm[2] += p2; sm[3] += p3;
    bf16x2 a = {(__bf16)p0, (__bf16)p1};
    bf16x2 b = {(__bf16)p2, (__bf16)p3};
    plo[nt] = __builtin_bit_cast(int, a);
    phi[nt] = __builtin_bit_cast(int, b);
  }
  float ssum = (sm[0] + sm[1]) + (sm[2] + sm[3]);
  ssum += __shfl_xor(ssum, 16);
  ssum += __shfl_xor(ssum, 32);
  const float inv = 1.f / ssum;  // for q = wv*16 + n16

  __syncthreads();  // all waves done reading kwin
  // ---- V coop load: global -> vwin[dh][232] (key = kr*16+kc) ----
  const __bf16* vtb = vt + base;
#pragma unroll
  for (int i = 0; i < 7; ++i) {
    int c = i * 256 + tid;  // 1792 16-B chunks: c = dh*28 + kr*2 + half
    int dh = c / 28, rem = c % 28;
    int kr = rem >> 1, half = rem & 1;
    bf16x8 d = *(const bf16x8*)(vtb + (size_t)dh * 4096 +
                                (wh0 + kr) * 64 + wc0 + half * 8);
    *(bf16x8*)&r1[dh * 232 + kr * 16 + half * 8] = d;
  }
  __syncthreads();

  // ---- PV: O[16q x 64dh]; A-frag gathered in-register per kt ----
  // pa elem j = P[key=kt*32+quad*8+j][q=n16]. Source lane holds key-col
  // quad_s*4+reg at q=n16 -> gather from lanes s0=((quad&1)*2)*16+n16 and
  // s1=s0+16; key-row parity: quads 0,1 need nt=2kt, quads 2,3 nt=2kt+1.
  f32x4 O[4] = {{0.f, 0.f, 0.f, 0.f},
                {0.f, 0.f, 0.f, 0.f},
                {0.f, 0.f, 0.f, 0.f},
                {0.f, 0.f, 0.f, 0.f}};
  const int s0 = ((quad & 1) << 5) + n16;
  const int s1 = s0 + 16;
  const bool hiq = quad >= 2;
#pragma unroll
  for (int kt = 0; kt < 7; ++kt) {
    const int nA = 2 * kt, nB = 2 * kt + 1;
    int a0 = __shfl(plo[nA], s0), a1 = __shfl(phi[nA], s0);
    int a2 = __shfl(plo[nA], s1), a3 = __shfl(phi[nA], s1);
    int b0 = __shfl(plo[nB], s0), b1 = __shfl(phi[nB], s0);
    int b2 = __shfl(plo[nB], s1), b3 = __shfl(phi[nB], s1);
    i32x4 pu = {hiq ? b0 : a0, hiq ? b1 : a1, hiq ? b2 : a2, hiq ? b3 : a3};
    bf16x8 pa = __builtin_bit_cast(bf16x8, pu);
    const int key0 = kt * 32 + quad * 8;
#pragma unroll
    for (int ntv = 0; ntv < 4; ++ntv) {
      bf16x8 vb = *(const bf16x8*)&r1[(ntv * 16 + n16) * 232 + key0];
      O[ntv] = __builtin_amdgcn_mfma_f32_16x16x32_bf16(pa, vb, O[ntv], 0, 0, 0);
    }
  }

  // ---- deferred normalization: inv for O-row q'=quad*4+reg via shfl ----
  float invr[4];
#pragma unroll
  for (int reg = 0; reg < 4; ++reg) invr[reg] = __shfl(inv, quad * 4 + reg);

  // ---- epilogue: ao[b][s][head*64+dh] bf16 (O rows: q=quad*4+reg) ----
  const int b = bh >> 3, head = bh & 7;
#pragma unroll
  for (int ntv = 0; ntv < 4; ++ntv)
#pragma unroll
    for (int reg = 0; reg < 4; ++reg) {
      int qe = wv * 16 + quad * 4 + reg;
      int s_q = (qh0 + (qe >> 3)) * 64 + qw0 + (qe & 7);
      int dh = ntv * 16 + n16;
      out[((size_t)(b * 4096 + s_q)) * 512 + head * 64 + dh] =
          (__bf16)(O[ntv][reg] * invr[reg]);
    }
}

extern "C" void kernel_launch(void* const* d_in, const int* in_sizes, int n_in,
                              void* d_out, int out_size, void* d_ws,
                              size_t ws_size, hipStream_t stream) {
  const float* x = (const float*)d_in[0];      // [2,64,64,512] fp32
  const float* w_qkv = (const float*)d_in[1];  // [1536,512] fp32
  const float* w_out = (const float*)d_in[2];  // [512,512] fp32
  float* out = (float*)d_out;                  // [2,64,64,512] fp32

  const size_t qelems = (size_t)2 * 8 * 4096 * 64;  // 4,194,304
  __bf16* q = (__bf16*)d_ws;
  __bf16* k = q + qelems;
  __bf16* vt = k + qelems;          // V transposed [bh][dh][s]
  __bf16* xb = vt + qelems;         // converted x; reused as ao
  __bf16* wqb = xb + qelems;        // converted w_qkv
  __bf16* wob = wqb + 1536 * 512;   // converted w_out
  __bf16* ao = xb;                  // attn out aliases xb (x dead after QKV)

  // Stage 0: fused fp32 -> bf16 (655360 chunks of 2x f32x4)
  cvt_all<<<dim3(2560), dim3(256), 0, stream>>>(x, w_qkv, w_out, xb, wqb, wob);

  // Stage 1: QKV GEMM: 64 i-tiles x 12 e-tiles = 768 blocks (3/CU)
  gemm_lds<true, 128><<<dim3(768), dim3(256), 0, stream>>>(
      xb, wqb, q, k, vt, nullptr, 12);
  // Stage 2: MFMA attention: 16 bh * 64 tiles = 1024 workgroups (4/CU)
  attn_mfma<<<dim3(1024), dim3(256), 0, stream>>>(q, k, vt, ao);
  // Stage 3: out GEMM: 64 i-tiles x 8 e-tiles = 512 blocks
  gemm_lds<false, 64><<<dim3(512), dim3(256), 0, stream>>>(
      ao, wob, nullptr, nullptr, nullptr, out, 8);
}

// Round 6
// 114.272 us; speedup vs baseline: 3.1815x; 1.0590x over previous
//
#include <hip/hip_runtime.h>
#include <hip/hip_bf16.h>

// NeighbourhoodAttnBlock: B=2, H=W=64, D=512, NH=8, DH=64, KERNEL=7
// Inputs fp32; output fp32. Internal pipeline bf16 MFMA.
// R6: gemm1 epilogue surgery. Each QKV block is purely q, k, or v
// (tsel = e0>>9 block-uniform). Old path: 64 scalar b16 global stores
// per thread; v-blocks scatter at 8KB lane stride (64 lines/wave-store).
// New path: C-tile staged in LDS (reuses Al|Wl as one 32KB buffer,
// xor-swizzled col^((row&7)<<3)), v-blocks write TRANSPOSED [e][i] via
// ds_write_b64; common drain = 8x {ds_read_b128 linear, 16B global
// store, perfectly coalesced}. Values/conversions identical -> bit-same.
// R5 heritage: XCD chunked swizzle all grids; attn swapped-QK^T,
// unnormalized P, deferred 1/ssum, 29.7KB LDS, 4 wg/CU, q*0.125 fold.

typedef __bf16 bf16x8 __attribute__((ext_vector_type(8)));
typedef __bf16 bf16x4 __attribute__((ext_vector_type(4)));
typedef __bf16 bf16x2 __attribute__((ext_vector_type(2)));
typedef float  f32x4  __attribute__((ext_vector_type(4)));
typedef int    i32x4  __attribute__((ext_vector_type(4)));

__global__ __launch_bounds__(256) void cvt_all(
    const float* __restrict__ x, const float* __restrict__ wq,
    const float* __restrict__ wo, __bf16* __restrict__ xb,
    __bf16* __restrict__ wqb, __bf16* __restrict__ wob) {
  // 655360 chunks of 2x f32x4 (32B read / 16B write per thread)
  int i = blockIdx.x * 256 + threadIdx.x;
  const float* src;
  __bf16* dst;
  int j = i;
  if (j < 524288) {
    src = x; dst = xb;
  } else if (j < 524288 + 98304) {
    j -= 524288; src = wq; dst = wqb;
  } else {
    j -= 524288 + 98304; src = wo; dst = wob;
  }
  f32x4 v0 = ((const f32x4*)src)[j * 2];
  f32x4 v1 = ((const f32x4*)src)[j * 2 + 1];
  bf16x8 o;
  o[0] = (__bf16)v0[0]; o[1] = (__bf16)v0[1];
  o[2] = (__bf16)v0[2]; o[3] = (__bf16)v0[3];
  o[4] = (__bf16)v1[0]; o[5] = (__bf16)v1[1];
  o[6] = (__bf16)v1[2]; o[7] = (__bf16)v1[3];
  ((bf16x8*)dst)[j] = o;
}

__device__ __forceinline__ void gload_lds16(const __bf16* g, __bf16* l) {
  __builtin_amdgcn_global_load_lds(
      (const __attribute__((address_space(1))) void*)g,
      (__attribute__((address_space(3))) void*)l, 16, 0, 0);
}

// C[i][e] = sum_d A[i][d] * W[e][d];  A:[M,512], W:[E,512] row-major bf16.
// 128xBN block tile, 4 waves x (64 x BN/2). BK=64 via two contiguous 32-col
// half-buffers (global_load_lds needs unpadded contiguity).
template <bool QKV, int BN>
__global__ __launch_bounds__(256, 3) void gemm_lds(
    const __bf16* __restrict__ A, const __bf16* __restrict__ W,
    __bf16* __restrict__ qo, __bf16* __restrict__ ko, __bf16* __restrict__ vo,
    float* __restrict__ co, int etiles) {
  constexpr int K = 512;
  constexpr int NT = BN / 32;
  constexpr int WHALF = BN * 32;
  // Single contiguous LDS pool: Al | Wl during K-loop; reused as the
  // 128xBN bf16 C-tile (ct) in the QKV epilogue (sizes match: 16384).
  __shared__ alignas(16) __bf16 shm[2 * 128 * 32 + 2 * WHALF];
  __bf16* Al = shm;
  __bf16* Wl = shm + 2 * 128 * 32;
  __bf16* ct = shm;
  const int tid = threadIdx.x;
  const int wv = tid >> 6, lane = tid & 63;
  const int n16 = lane & 15, quad = lane >> 4;
  // T1 XCD chunked swizzle (gridDim.x % 8 == 0 -> bijective):
  // each XCD gets a contiguous chunk of tiles -> A-panels + W fit its L2.
  const int nper = (int)gridDim.x >> 3;
  const int wg = (blockIdx.x & 7) * nper + (blockIdx.x >> 3);
  const int bi = wg / etiles, be = wg % etiles;
  const int i0 = bi << 7, e0 = be * BN;
  const int wm = (wv & 1) << 6, we = (wv >> 1) * (BN / 2);

  const int srow = (wv << 4) + (lane >> 2);
  const int scol = (lane & 3) << 3;
  const __bf16* gA = A + (size_t)(i0 + srow) * K + scol;
  const __bf16* gW = W + (size_t)(e0 + srow) * K + scol;
  const int soff = (wv << 9) + (lane << 3);

  f32x4 acc[4][NT];
#pragma unroll
  for (int a = 0; a < 4; ++a)
#pragma unroll
    for (int b = 0; b < NT; ++b) acc[a][b] = (f32x4){0.f, 0.f, 0.f, 0.f};

  for (int k0 = 0; k0 < K; k0 += 64) {
    if (k0) __syncthreads();
#pragma unroll
    for (int h = 0; h < 2; ++h) {
      gload_lds16(gA + k0 + h * 32, &Al[h * 4096 + soff]);
      gload_lds16(gA + (size_t)64 * K + k0 + h * 32,
                  &Al[h * 4096 + 64 * 32 + soff]);
      gload_lds16(gW + k0 + h * 32, &Wl[h * WHALF + soff]);
      if (BN == 128)
        gload_lds16(gW + (size_t)64 * K + k0 + h * 32,
                    &Wl[h * WHALF + 64 * 32 + soff]);
    }
    __syncthreads();

#pragma unroll
    for (int h = 0; h < 2; ++h) {
      bf16x8 af[4], wf[NT];
#pragma unroll
      for (int t = 0; t < 4; ++t)
        af[t] = *(const bf16x8*)&Al[h * 4096 + (wm + t * 16 + n16) * 32 +
                                    quad * 8];
#pragma unroll
      for (int t = 0; t < NT; ++t)
        wf[t] = *(const bf16x8*)&Wl[h * WHALF + (we + t * 16 + n16) * 32 +
                                    quad * 8];
#pragma unroll
      for (int mt = 0; mt < 4; ++mt)
#pragma unroll
        for (int nt = 0; nt < NT; ++nt)
          acc[mt][nt] = __builtin_amdgcn_mfma_f32_16x16x32_bf16(
              af[mt], wf[nt], acc[mt][nt], 0, 0, 0);
    }
  }

  if (QKV) {
    // ---- LDS re-layout epilogue (block type is uniform: tsel=e0>>9) ----
    __syncthreads();  // all waves done reading Al/Wl
    const int tsel = e0 >> 9;  // 0=q, 1=k, 2=v
    if (tsel == 2) {
      // transposed ct[e][i ^ sw] via b64 (rg values are consecutive i)
#pragma unroll
      for (int mt = 0; mt < 4; ++mt)
#pragma unroll
        for (int nt = 0; nt < NT; ++nt) {
          f32x4 f = acc[mt][nt];
          int el = we + nt * 16 + n16;
          int il = wm + mt * 16 + quad * 4;
          bf16x4 h4 = {(__bf16)f[0], (__bf16)f[1], (__bf16)f[2], (__bf16)f[3]};
          *(bf16x4*)&ct[el * 128 + (il ^ ((el & 7) << 3))] = h4;
        }
    } else {
      const float qs = (tsel == 0) ? 0.125f : 1.0f;  // fold attn scale into q
#pragma unroll
      for (int mt = 0; mt < 4; ++mt)
#pragma unroll
        for (int nt = 0; nt < NT; ++nt) {
          f32x4 f = acc[mt][nt];
          int el = we + nt * 16 + n16;
#pragma unroll
          for (int rg = 0; rg < 4; ++rg) {
            int il = wm + mt * 16 + quad * 4 + rg;
            ct[il * 128 + (el ^ ((il & 7) << 3))] = (__bf16)(f[rg] * qs);
          }
        }
    }
    __syncthreads();
    // ---- common drain: 2048 chunks of 8, fully coalesced 16B stores ----
    const int b = i0 >> 12;
    const int s0 = i0 & 4095;
#pragma unroll
    for (int u = 0; u < 8; ++u) {
      int cid = u * 256 + tid;
      int row = cid >> 4, c8 = (cid & 15) << 3;
      bf16x8 d = *(const bf16x8*)&ct[row * 128 + (c8 ^ ((row & 7) << 3))];
      if (tsel == 2) {
        int e = e0 + row;  // row = e_local
        int head = (e >> 6) & 7, dh = e & 63;
        *(bf16x8*)&vo[((size_t)(b * 8 + head) * 64 + dh) * 4096 + s0 + c8] = d;
      } else {
        int e = e0 + c8;   // row = i_local
        int head = (e >> 6) & 7, dh = e & 63;
        size_t off = ((size_t)(b * 8 + head) * 4096 + (s0 + row)) * 64 + dh;
        *(bf16x8*)&((tsel == 0) ? qo : ko)[off] = d;
      }
    }
  } else {
    // ---- fp32 C output (out GEMM), unchanged ----
#pragma unroll
    for (int mt = 0; mt < 4; ++mt)
#pragma unroll
      for (int nt = 0; nt < NT; ++nt) {
        f32x4 f = acc[mt][nt];
        int e = e0 + we + nt * 16 + n16;
#pragma unroll
        for (int rg = 0; rg < 4; ++rg) {
          int i = i0 + wm + mt * 16 + quad * 4 + rg;
          co[(size_t)i * 512 + e] = f[rg];
        }
      }
  }
}

// MFMA neighbourhood attention, swapped-QK^T / in-register-P version.
// One workgroup per (bh, 8x8 query tile). LDS = kwin/vwin only (29.7 KB).
// Phase 1: K window -> LDS (pre-swizzled gload_lds); S^T = mfma(K,Q);
//          per-lane mask + softmax (one q per lane); P packed UNNORMALIZED
//          to bf16 regs (exp <= 1); 1/ssum applied to O after PV.
// Phase 2: barrier; V window -> LDS [dh][232]; PV with per-kt in-register
//          P gather (8 shfl quad-exchange) -> mfma(pa, vb).
__global__ __launch_bounds__(256, 4) void attn_mfma(
    const __bf16* __restrict__ q, const __bf16* __restrict__ k,
    const __bf16* __restrict__ vt, __bf16* __restrict__ out) {
  __shared__ alignas(16) __bf16 r1[14848];  // kwin / vwin[64][232]
  const int tid = threadIdx.x;
  const int wv = tid >> 6;
  const int lane = tid & 63;
  const int n16 = lane & 15, quad = lane >> 4;
  // T1 XCD chunked swizzle: 1024 wgs -> each XCD owns 128 contiguous wgs
  // = 2 whole bh (q+k+vt = 3.1MB < 4MB L2): window overlap re-reads hit L2.
  const int wg = ((blockIdx.x & 7) << 7) + (blockIdx.x >> 3);
  const int bh = wg >> 6;
  const int tile = wg & 63;
  const int qh0 = (tile >> 3) << 3, qw0 = (tile & 7) << 3;
  int wh0 = qh0 - 3; wh0 = wh0 < 0 ? 0 : (wh0 > 50 ? 50 : wh0);
  int wc0 = qw0 - 3; wc0 = wc0 < 0 ? 0 : (wc0 > 48 ? 48 : wc0);
  wc0 &= ~1;  // window covers [qw0-3, qw0+10]
  const size_t base = (size_t)bh * 4096 * 64;

  // ---- Q frags (B-operand of swapped QK^T; layout identical to A-frag) ----
  const int qi = wv * 16 + n16;  // this lane's query (softmax row)
  const int sq = (qh0 + (qi >> 3)) * 64 + qw0 + (qi & 7);
  const __bf16* qp = q + base + (size_t)sq * 64 + quad * 8;
  bf16x8 bq0 = *(const bf16x8*)qp;
  bf16x8 bq1 = *(const bf16x8*)(qp + 32);

  // ---- K window staging: global_load_lds, source pre-swizzled (R3-verified)
  const __bf16* kbase = k + base;
#pragma unroll
  for (int i = 0; i < 7; ++i) {
    int ch = i * 256 + tid;           // 1792 16-B chunks
    int kr = ch >> 7, wi = ch & 127;
    int kc = wi >> 3, dh8 = wi & 7;
    gload_lds16(kbase + (size_t)((wh0 + kr) * 64 + wc0 + kc) * 64 +
                    ((dh8 ^ (kc & 7)) * 8),
                &r1[ch * 8]);
  }
  __syncthreads();

  // ---- swapped QK^T: S[nt] = S^T tile; lane = [key=nt*16+quad*4+reg][q=n16]
  f32x4 S[14];
  const int sw1 = ((quad ^ (n16 & 7)) * 8);
  const int sw2 = (((4 + quad) ^ (n16 & 7)) * 8);
#pragma unroll
  for (int nt = 0; nt < 14; ++nt) {
    int key = nt * 16 + n16;
    bf16x8 kf0 = *(const bf16x8*)&r1[key * 64 + sw1];
    bf16x8 kf1 = *(const bf16x8*)&r1[key * 64 + sw2];
    f32x4 s = {0.f, 0.f, 0.f, 0.f};
    s = __builtin_amdgcn_mfma_f32_16x16x32_bf16(kf0, bq0, s, 0, 0, 0);
    s = __builtin_amdgcn_mfma_f32_16x16x32_bf16(kf1, bq1, s, 0, 0, 0);
    S[nt] = s;
  }

  // ---- mask (scale already folded into q): one query per lane ----
  const int qh = qh0 + (qi >> 3), qw = qw0 + (qi & 7);
  int sh = qh - 3; sh = sh < 0 ? 0 : (sh > 57 ? 57 : sh);
  int sw = qw - 3; sw = sw < 0 ? 0 : (sw > 57 ? 57 : sw);
  const int lo = sh - wh0;  // valid key-rows: nt in [lo, lo+7)
  bool wok[4];
#pragma unroll
  for (int reg = 0; reg < 4; ++reg) {
    int kw = wc0 + quad * 4 + reg;  // fixed key col per (lane,reg)
    wok[reg] = (kw >= sw) && (kw < sw + 7);
  }
  float mx[4] = {-1e30f, -1e30f, -1e30f, -1e30f};
#pragma unroll
  for (int nt = 0; nt < 14; ++nt) {
    bool rok = (unsigned)(nt - lo) < 7u;
#pragma unroll
    for (int reg = 0; reg < 4; ++reg) {
      float val = (rok && wok[reg]) ? S[nt][reg] : -1e30f;
      S[nt][reg] = val;
      mx[reg] = mx[reg] > val ? mx[reg] : val;
    }
  }
  float m = fmaxf(fmaxf(mx[0], mx[1]), fmaxf(mx[2], mx[3]));
  m = fmaxf(m, __shfl_xor(m, 16));
  m = fmaxf(m, __shfl_xor(m, 32));

  // ---- exp + row sum; pack UNNORMALIZED P (exp <= 1, bf16-safe) ----
  int plo[14], phi[14];
  float sm[4] = {0.f, 0.f, 0.f, 0.f};
#pragma unroll
  for (int nt = 0; nt < 14; ++nt) {
    float p0 = __expf(S[nt][0] - m);
    float p1 = __expf(S[nt][1] - m);
    float p2 = __expf(S[nt][2] - m);
    float p3 = __expf(S[nt][3] - m);
    sm[0] += p0; sm[1] += p1; sm[2] += p2; sm[3] += p3;
    bf16x2 a = {(__bf16)p0, (__bf16)p1};
    bf16x2 b = {(__bf16)p2, (__bf16)p3};
    plo[nt] = __builtin_bit_cast(int, a);
    phi[nt] = __builtin_bit_cast(int, b);
  }
  float ssum = (sm[0] + sm[1]) + (sm[2] + sm[3]);
  ssum += __shfl_xor(ssum, 16);
  ssum += __shfl_xor(ssum, 32);
  const float inv = 1.f / ssum;  // for q = wv*16 + n16

  __syncthreads();  // all waves done reading kwin
  // ---- V coop load: global -> vwin[dh][232] (key = kr*16+kc) ----
  const __bf16* vtb = vt + base;
#pragma unroll
  for (int i = 0; i < 7; ++i) {
    int c = i * 256 + tid;  // 1792 16-B chunks: c = dh*28 + kr*2 + half
    int dh = c / 28, rem = c % 28;
    int kr = rem >> 1, half = rem & 1;
    bf16x8 d = *(const bf16x8*)(vtb + (size_t)dh * 4096 +
                                (wh0 + kr) * 64 + wc0 + half * 8);
    *(bf16x8*)&r1[dh * 232 + kr * 16 + half * 8] = d;
  }
  __syncthreads();

  // ---- PV: O[16q x 64dh]; A-frag gathered in-register per kt ----
  // pa elem j = P[key=kt*32+quad*8+j][q=n16]. Source lane holds key-col
  // quad_s*4+reg at q=n16 -> gather from lanes s0=((quad&1)*2)*16+n16 and
  // s1=s0+16; key-row parity: quads 0,1 need nt=2kt, quads 2,3 nt=2kt+1.
  f32x4 O[4] = {{0.f, 0.f, 0.f, 0.f},
                {0.f, 0.f, 0.f, 0.f},
                {0.f, 0.f, 0.f, 0.f},
                {0.f, 0.f, 0.f, 0.f}};
  const int s0 = ((quad & 1) << 5) + n16;
  const int s1 = s0 + 16;
  const bool hiq = quad >= 2;
#pragma unroll
  for (int kt = 0; kt < 7; ++kt) {
    const int nA = 2 * kt, nB = 2 * kt + 1;
    int a0 = __shfl(plo[nA], s0), a1 = __shfl(phi[nA], s0);
    int a2 = __shfl(plo[nA], s1), a3 = __shfl(phi[nA], s1);
    int b0 = __shfl(plo[nB], s0), b1 = __shfl(phi[nB], s0);
    int b2 = __shfl(plo[nB], s1), b3 = __shfl(phi[nB], s1);
    i32x4 pu = {hiq ? b0 : a0, hiq ? b1 : a1, hiq ? b2 : a2, hiq ? b3 : a3};
    bf16x8 pa = __builtin_bit_cast(bf16x8, pu);
    const int key0 = kt * 32 + quad * 8;
#pragma unroll
    for (int ntv = 0; ntv < 4; ++ntv) {
      bf16x8 vb = *(const bf16x8*)&r1[(ntv * 16 + n16) * 232 + key0];
      O[ntv] = __builtin_amdgcn_mfma_f32_16x16x32_bf16(pa, vb, O[ntv], 0, 0, 0);
    }
  }

  // ---- deferred normalization: inv for O-row q'=quad*4+reg via shfl ----
  float invr[4];
#pragma unroll
  for (int reg = 0; reg < 4; ++reg) invr[reg] = __shfl(inv, quad * 4 + reg);

  // ---- epilogue: ao[b][s][head*64+dh] bf16 (O rows: q=quad*4+reg) ----
  const int b = bh >> 3, head = bh & 7;
#pragma unroll
  for (int ntv = 0; ntv < 4; ++ntv)
#pragma unroll
    for (int reg = 0; reg < 4; ++reg) {
      int qe = wv * 16 + quad * 4 + reg;
      int s_q = (qh0 + (qe >> 3)) * 64 + qw0 + (qe & 7);
      int dh = ntv * 16 + n16;
      out[((size_t)(b * 4096 + s_q)) * 512 + head * 64 + dh] =
          (__bf16)(O[ntv][reg] * invr[reg]);
    }
}

extern "C" void kernel_launch(void* const* d_in, const int* in_sizes, int n_in,
                              void* d_out, int out_size, void* d_ws,
                              size_t ws_size, hipStream_t stream) {
  const float* x = (const float*)d_in[0];      // [2,64,64,512] fp32
  const float* w_qkv = (const float*)d_in[1];  // [1536,512] fp32
  const float* w_out = (const float*)d_in[2];  // [512,512] fp32
  float* out = (float*)d_out;                  // [2,64,64,512] fp32

  const size_t qelems = (size_t)2 * 8 * 4096 * 64;  // 4,194,304
  __bf16* q = (__bf16*)d_ws;
  __bf16* k = q + qelems;
  __bf16* vt = k + qelems;          // V transposed [bh][dh][s]
  __bf16* xb = vt + qelems;         // converted x; reused as ao
  __bf16* wqb = xb + qelems;        // converted w_qkv
  __bf16* wob = wqb + 1536 * 512;   // converted w_out
  __bf16* ao = xb;                  // attn out aliases xb (x dead after QKV)

  // Stage 0: fused fp32 -> bf16 (655360 chunks of 2x f32x4)
  cvt_all<<<dim3(2560), dim3(256), 0, stream>>>(x, w_qkv, w_out, xb, wqb, wob);

  // Stage 1: QKV GEMM: 64 i-tiles x 12 e-tiles = 768 blocks (3/CU)
  gemm_lds<true, 128><<<dim3(768), dim3(256), 0, stream>>>(
      xb, wqb, q, k, vt, nullptr, 12);
  // Stage 2: MFMA attention: 16 bh * 64 tiles = 1024 workgroups (4/CU)
  attn_mfma<<<dim3(1024), dim3(256), 0, stream>>>(q, k, vt, ao);
  // Stage 3: out GEMM: 64 i-tiles x 8 e-tiles = 512 blocks
  gemm_lds<false, 64><<<dim3(512), dim3(256), 0, stream>>>(
      ao, wob, nullptr, nullptr, nullptr, out, 8);
}